// Round 13
// baseline (2404.901 us; speedup 1.0000x reference)
//
#include <hip/hip_runtime.h>
#include <hip/hip_bf16.h>
#include <float.h>
#include <math.h>

#define NB 4
#define NN 8192
#define FF 64
#define MM 2048
#define KK 32
#define HH 64

#define FT 512          // fps threads (8 waves)

typedef float v2f __attribute__((ext_vector_type(2)));

// forced packed-FP32 VOP3P ops (gfx90a+/gfx950); 64-bit operands -> VGPR pairs
__device__ __forceinline__ v2f pk_add(v2f a, v2f b) {
    v2f r; asm("v_pk_add_f32 %0, %1, %2" : "=v"(r) : "v"(a), "v"(b)); return r;
}
__device__ __forceinline__ v2f pk_mul(v2f a, v2f b) {
    v2f r; asm("v_pk_mul_f32 %0, %1, %2" : "=v"(r) : "v"(a), "v"(b)); return r;
}

// DPP float-max step (old = -inf identity), validated r4/r11.
#define DPP_FMAX(v, ctrl, rmask)                                                \
    { int _t = __builtin_amdgcn_update_dpp((int)0xff800000, __float_as_int(v),  \
                   (ctrl), (rmask), 0xf, false);                                \
      (v) = fmaxf((v), __int_as_float(_t)); }
#define DPP_FMAX6(v)  DPP_FMAX(v,0x111,0xf) DPP_FMAX(v,0x112,0xf) \
                      DPP_FMAX(v,0x114,0xf) DPP_FMAX(v,0x118,0xf) \
                      DPP_FMAX(v,0x142,0xa) DPP_FMAX(v,0x143,0xc)

// DPP int-min step (old = INT_MAX identity), validated r11.
#define DPP_IMIN(v, ctrl, rmask)                                                \
    { int _t = __builtin_amdgcn_update_dpp((int)0x7fffffff, (v),                \
                   (ctrl), (rmask), 0xf, false);                                \
      (v) = min((v), _t); }
#define DPP_IMIN6(v)  DPP_IMIN(v,0x111,0xf) DPP_IMIN(v,0x112,0xf) \
                      DPP_IMIN(v,0x114,0xf) DPP_IMIN(v,0x118,0xf) \
                      DPP_IMIN(v,0x142,0xa) DPP_IMIN(v,0x143,0xc)

__device__ __forceinline__ float readlane_f(float v, int l) {
    return __int_as_float(__builtin_amdgcn_readlane(__float_as_int(v), l));
}

// comparator for (value, idx-bits) in float2: max value, tie -> lower idx (r9)
__device__ __forceinline__ float2 argmax2(float2 a, float2 b) {
    const int ia = __float_as_int(a.y), ib = __float_as_int(b.y);
    return (b.x > a.x || (b.x == a.x && ib < ia)) ? b : a;
}

// ---------------- Kernel 1: exact FPS, packed math + one-barrier tail ----------------
__global__ __launch_bounds__(FT) void fps_kernel(
    const float* __restrict__ pos,
    int* __restrict__ samp,
    float* __restrict__ centers_out,
    float* __restrict__ batch_out)
{
#pragma clang fp contract(off)
    __shared__ float4 pts4[NN];          // natural order; winner-fetch only (128 KB)
    __shared__ float2 slots[2][8];       // parity-buffered per-wave (max, minidx)

    const int b = blockIdx.x;
    const float* pb = pos + (size_t)b * NN * 3;
    const int tid = threadIdx.x;
    const int w   = tid >> 6;
    const int lane = tid & 63;

    // ---- stage points; prefill batch ids ----
    for (int j = tid; j < NN; j += FT)
        pts4[j] = make_float4(pb[j * 3 + 0], pb[j * 3 + 1], pb[j * 3 + 2], 0.0f);
    for (int j = tid; j < MM; j += FT) batch_out[b * MM + j] = (float)b;
    __syncthreads();

    // ---- 16 points/thread as 8 packed coordinate pairs; dists as scalars ----
    // pair j: indices (2j)*FT+tid (.x) and (2j+1)*FT+tid (.y)
    v2f pxv[8], pyv[8], pzv[8];
    float dvx[8], dvy[8];
#pragma unroll
    for (int j = 0; j < 8; ++j) {
        const float4 p0 = pts4[(2 * j) * FT + tid];
        const float4 p1 = pts4[(2 * j + 1) * FT + tid];
        pxv[j] = (v2f){p0.x, p1.x};
        pyv[j] = (v2f){p0.y, p1.y};
        pzv[j] = (v2f){p0.z, p1.z};
        dvx[j] = INFINITY; dvy[j] = INFINITY;
    }

    int   cur = 0;
    float lx = pb[0], ly = pb[1], lz = pb[2];

    for (int s = 0; s < MM; ++s) {
#pragma clang fp contract(off)
        if (tid == 0) {
            samp[b * MM + s] = cur;
            centers_out[((size_t)b * MM + s) * 3 + 0] = lx;
            centers_out[((size_t)b * MM + s) * 3 + 1] = ly;
            centers_out[((size_t)b * MM + s) * 3 + 2] = lz;
        }
        if (s == MM - 1) break;   // last argmax unused by the reference

        // pre-negated center: p + (-l) is bit-identical to p - l (IEEE RN)
        const v2f nlx = (v2f){-lx, -lx};
        const v2f nly = (v2f){-ly, -ly};
        const v2f nlz = (v2f){-lz, -lz};

        // ---- phase 1: packed distance update (independent pairs pipeline) ----
#pragma unroll
        for (int j = 0; j < 8; ++j) {
            const v2f dx = pk_add(pxv[j], nlx);
            const v2f dy = pk_add(pyv[j], nly);
            const v2f dz = pk_add(pzv[j], nlz);
            // exact ref order: ((dx*dx + dy*dy) + dz*dz), separate mul/add
            const v2f d2 = pk_add(pk_add(pk_mul(dx, dx), pk_mul(dy, dy)),
                                  pk_mul(dz, dz));
            dvx[j] = fminf(dvx[j], d2.x);   // jnp.minimum, exact
            dvy[j] = fminf(dvy[j], d2.y);
        }
        // ---- thread max: depth-4 tree (15 fmax, short dependency chain) ----
        const float m0 = fmaxf(fmaxf(dvx[0], dvy[0]), fmaxf(dvx[1], dvy[1]));
        const float m1 = fmaxf(fmaxf(dvx[2], dvy[2]), fmaxf(dvx[3], dvy[3]));
        const float m2 = fmaxf(fmaxf(dvx[4], dvy[4]), fmaxf(dvx[5], dvy[5]));
        const float m3 = fmaxf(fmaxf(dvx[6], dvy[6]), fmaxf(dvx[7], dvy[7]));
        const float tv = fmaxf(fmaxf(m0, m1), fmaxf(m2, m3));

        // ---- wave value max -> SGPR broadcast ----
        float wv = tv;
        DPP_FMAX6(wv)                              // lane63: wave max
        const float wmax = readlane_f(wv, 63);     // uniform broadcast

        // ---- index recovery: only lanes holding the wave max scan (exec-sparse
        //      within the wave; >=1 lane per wave). descending order keeps the
        //      LOWEST matching index (ref first-max tie-break); == on stored
        //      values is exact (all dists >= +0.0, no NaN). ----
        int cand = 0x7fffffff;
        if (tv == wmax) {
#pragma unroll
            for (int j = 7; j >= 0; --j) {
                cand = (dvy[j] == wmax) ? (2 * j + 1) * FT + tid : cand;
                cand = (dvx[j] == wmax) ? (2 * j) * FT + tid     : cand;
            }
        }
        DPP_IMIN6(cand)                            // lane63: wave min matching idx

        // ---- one slot write, ONE barrier, 8-slot tree, winner fetch ----
        const int par = s & 1;
        if (lane == 63) slots[par][w] = make_float2(wmax, __int_as_float(cand));
        __syncthreads();

        const float2 s0 = slots[par][0], s1 = slots[par][1];
        const float2 s2 = slots[par][2], s3 = slots[par][3];
        const float2 s4 = slots[par][4], s5 = slots[par][5];
        const float2 s6 = slots[par][6], s7 = slots[par][7];
        const float2 a0 = argmax2(s0, s1), a1 = argmax2(s2, s3);
        const float2 a2 = argmax2(s4, s5), a3 = argmax2(s6, s7);
        const float2 b0 = argmax2(a0, a1), b1 = argmax2(a2, a3);
        const float2 win = argmax2(b0, b1);

        cur = __float_as_int(win.y);
        const float4 wp = pts4[cur];               // broadcast read, conflict-free
        lx = wp.x; ly = wp.y; lz = wp.z;
    }
}

// ---------------- Kernel 2: radius-KNN, one wave per center ----------------
#define CAP 256
__global__ __launch_bounds__(256) void knn_kernel(
    const float* __restrict__ pos,
    const int* __restrict__ samp,
    int* __restrict__ nbr,
    int* __restrict__ cntbuf)
{
    const int wave = threadIdx.x >> 6;
    const int lane = threadIdx.x & 63;
    const int c = blockIdx.x * 4 + wave;
    const int b = c >> 11;
    const float* pb = pos + (size_t)b * NN * 3;

    __shared__ float sd2[4][CAP];
    __shared__ int   sid[4][CAP];

    const int ctr = samp[c];
    const float cx = pb[ctr * 3 + 0];
    const float cy = pb[ctr * 3 + 1];
    const float cz = pb[ctr * 3 + 2];
    const float R2 = (float)(0.1 * 0.1);

    int cnt = 0;
    for (int r = 0; r < NN / 64; ++r) {
        const int g = r * 64 + lane;
        float dx = __fsub_rn(cx, pb[g * 3 + 0]);
        float dy = __fsub_rn(cy, pb[g * 3 + 1]);
        float dz = __fsub_rn(cz, pb[g * 3 + 2]);
        float d2 = __fadd_rn(__fadd_rn(__fmul_rn(dx, dx), __fmul_rn(dy, dy)),
                             __fmul_rn(dz, dz));
        const bool pred = (d2 <= R2);
        const unsigned long long mask = __ballot(pred);
        const int before = __popcll(mask & ((1ull << lane) - 1ull));
        if (pred) {
            const int slot = cnt + before;
            if (slot < CAP) { sd2[wave][slot] = d2; sid[wave][slot] = g; }
        }
        cnt += __popcll(mask);
    }
    if (cnt > CAP) cnt = CAP;
    __syncthreads();

    for (int ci = lane; ci < cnt; ci += 64) {
        const float dc = sd2[wave][ci];
        const int   ic = sid[wave][ci];
        int rank = 0;
        for (int j = 0; j < cnt; ++j) {
            const float dj = sd2[wave][j];
            const int   ij = sid[wave][j];
            rank += (dj < dc || (dj == dc && ij < ic)) ? 1 : 0;
        }
        if (rank < KK) nbr[c * KK + rank] = ic;
    }
    if (lane == 0) cntbuf[c] = (cnt < KK) ? cnt : KK;
}

// ---------------- Kernel 3: gather + MLP + max-pool, one wave per center ----
__global__ __launch_bounds__(256) void mlp_kernel(
    const float* __restrict__ x,
    const float* __restrict__ pos,
    const float* __restrict__ W1,
    const float* __restrict__ b1,
    const float* __restrict__ W2,
    const float* __restrict__ b2,
    const int* __restrict__ nbr,
    const int* __restrict__ cntbuf,
    const float* __restrict__ centers,
    float* __restrict__ out)
{
    __shared__ float WT[64 * 68];
    __shared__ float featL[4][32 * 68];

    const int tid = threadIdx.x, wave = tid >> 6, lane = tid & 63;
    const int c = blockIdx.x * 4 + wave;
    const int b = c >> 11;
    const int cnt = cntbuf[c];

    for (int idx = tid; idx < 67 * 64; idx += 256) {
        const int i = idx >> 6, h = idx & 63;
        WT[h * 68 + i] = W1[idx];
    }
    if (tid < 64) WT[tid * 68 + 67] = 0.0f;

    const float ctr0 = centers[c * 3 + 0];
    const float ctr1 = centers[c * 3 + 1];
    const float ctr2 = centers[c * 3 + 2];
    for (int k = 0; k < cnt; ++k) {
        const int j = nbr[c * KK + k];
        featL[wave][k * 68 + lane] = x[((size_t)b * NN + j) * FF + lane];
        if (lane < 3) {
            const float pj = pos[((size_t)b * NN + j) * 3 + lane];
            const float ci = (lane == 0) ? ctr0 : ((lane == 1) ? ctr1 : ctr2);
            featL[wave][k * 68 + 64 + lane] = __fsub_rn(pj, ci);
        }
        if (lane == 3) featL[wave][k * 68 + 67] = 0.0f;
    }
    __syncthreads();

    float wreg[68];
#pragma unroll
    for (int i4 = 0; i4 < 17; ++i4) {
        const float4 v = *(const float4*)&WT[lane * 68 + i4 * 4];
        wreg[i4 * 4 + 0] = v.x; wreg[i4 * 4 + 1] = v.y;
        wreg[i4 * 4 + 2] = v.z; wreg[i4 * 4 + 3] = v.w;
    }
    const float bias1 = b1[lane];
    for (int k = 0; k < cnt; ++k) {
        float acc = bias1;
#pragma unroll
        for (int i4 = 0; i4 < 17; ++i4) {
            const float4 f = *(const float4*)&featL[wave][k * 68 + i4 * 4];
            acc = fmaf(f.x, wreg[i4 * 4 + 0], acc);
            acc = fmaf(f.y, wreg[i4 * 4 + 1], acc);
            acc = fmaf(f.z, wreg[i4 * 4 + 2], acc);
            acc = fmaf(f.w, wreg[i4 * 4 + 3], acc);
        }
        featL[wave][k * 68 + lane] = fmaxf(acc, 0.0f);
    }
    __syncthreads();

    for (int idx = tid; idx < 64 * 64; idx += 256) {
        const int i = idx >> 6, h = idx & 63;
        WT[h * 68 + i] = W2[idx];
    }
    __syncthreads();

#pragma unroll
    for (int i4 = 0; i4 < 16; ++i4) {
        const float4 v = *(const float4*)&WT[lane * 68 + i4 * 4];
        wreg[i4 * 4 + 0] = v.x; wreg[i4 * 4 + 1] = v.y;
        wreg[i4 * 4 + 2] = v.z; wreg[i4 * 4 + 3] = v.w;
    }
    const float bias2 = b2[lane];
    float m = -INFINITY;
    for (int k = 0; k < cnt; ++k) {
        float acc = bias2;
#pragma unroll
        for (int i4 = 0; i4 < 16; ++i4) {
            const float4 f = *(const float4*)&featL[wave][k * 68 + i4 * 4];
            acc = fmaf(f.x, wreg[i4 * 4 + 0], acc);
            acc = fmaf(f.y, wreg[i4 * 4 + 1], acc);
            acc = fmaf(f.z, wreg[i4 * 4 + 2], acc);
            acc = fmaf(f.w, wreg[i4 * 4 + 3], acc);
        }
        m = fmaxf(m, fmaxf(acc, 0.0f));
    }
    out[(size_t)c * HH + lane] = (cnt > 0) ? m : 0.0f;
}

extern "C" void kernel_launch(void* const* d_in, const int* in_sizes, int n_in,
                              void* d_out, int out_size, void* d_ws, size_t ws_size,
                              hipStream_t stream) {
    const float* x   = (const float*)d_in[0];
    const float* pos = (const float*)d_in[1];
    const float* W1  = (const float*)d_in[3];
    const float* b1  = (const float*)d_in[4];
    const float* W2  = (const float*)d_in[5];
    const float* b2  = (const float*)d_in[6];

    float* out         = (float*)d_out;
    float* centers_out = out + (size_t)NB * MM * HH;
    float* batch_out   = centers_out + (size_t)NB * MM * 3;

    char* ws = (char*)d_ws;
    int* samp   = (int*)ws;
    int* cntbuf = (int*)(ws + (size_t)NB * MM * 4);
    int* nbr    = (int*)(ws + (size_t)2 * NB * MM * 4);

    fps_kernel<<<NB, FT, 0, stream>>>(pos, samp, centers_out, batch_out);
    knn_kernel<<<(NB * MM) / 4, 256, 0, stream>>>(pos, samp, nbr, cntbuf);
    mlp_kernel<<<(NB * MM) / 4, 256, 0, stream>>>(x, pos, W1, b1, W2, b2,
                                                  nbr, cntbuf, centers_out, out);
}

// Round 14
// 2232.649 us; speedup vs baseline: 1.0772x; 1.0772x over previous
//
#include <hip/hip_runtime.h>
#include <hip/hip_bf16.h>
#include <float.h>
#include <math.h>

#define NB 4
#define NN 8192
#define FF 64
#define MM 2048
#define KK 32
#define HH 64

#define FT 512          // fps threads (8 waves)

typedef float v2f __attribute__((ext_vector_type(2)));

// DPP float-max step (old = -inf identity), validated r4/r11/r13.
#define DPP_FMAX(v, ctrl, rmask)                                                \
    { int _t = __builtin_amdgcn_update_dpp((int)0xff800000, __float_as_int(v),  \
                   (ctrl), (rmask), 0xf, false);                                \
      (v) = fmaxf((v), __int_as_float(_t)); }
#define DPP_FMAX6(v)  DPP_FMAX(v,0x111,0xf) DPP_FMAX(v,0x112,0xf) \
                      DPP_FMAX(v,0x114,0xf) DPP_FMAX(v,0x118,0xf) \
                      DPP_FMAX(v,0x142,0xa) DPP_FMAX(v,0x143,0xc)

// DPP int-min step (old = INT_MAX identity), validated r11/r13.
#define DPP_IMIN(v, ctrl, rmask)                                                \
    { int _t = __builtin_amdgcn_update_dpp((int)0x7fffffff, (v),                \
                   (ctrl), (rmask), 0xf, false);                                \
      (v) = min((v), _t); }
#define DPP_IMIN6(v)  DPP_IMIN(v,0x111,0xf) DPP_IMIN(v,0x112,0xf) \
                      DPP_IMIN(v,0x114,0xf) DPP_IMIN(v,0x118,0xf) \
                      DPP_IMIN(v,0x142,0xa) DPP_IMIN(v,0x143,0xc)

__device__ __forceinline__ float readlane_f(float v, int l) {
    return __int_as_float(__builtin_amdgcn_readlane(__float_as_int(v), l));
}

// comparator for (value, idx-bits) in float2: max value, tie -> lower idx (r9/r13)
__device__ __forceinline__ float2 argmax2(float2 a, float2 b) {
    const int ia = __float_as_int(a.y), ib = __float_as_int(b.y);
    return (b.x > a.x || (b.x == a.x && ib < ia)) ? b : a;
}

// ---------------- Kernel 1: exact FPS = r11 phase-1 + r13 one-barrier tail ----------------
__global__ __launch_bounds__(FT) void fps_kernel(
    const float* __restrict__ pos,
    int* __restrict__ samp,
    float* __restrict__ centers_out,
    float* __restrict__ batch_out)
{
#pragma clang fp contract(off)
    __shared__ float4 pts4[NN];          // natural order; winner-fetch only (128 KB)
    __shared__ float2 slots[2][8];       // parity-buffered per-wave (max, minidx)

    const int b = blockIdx.x;
    const float* pb = pos + (size_t)b * NN * 3;
    const int tid = threadIdx.x;
    const int w   = tid >> 6;
    const int lane = tid & 63;

    // ---- stage points; prefill batch ids ----
    for (int j = tid; j < NN; j += FT)
        pts4[j] = make_float4(pb[j * 3 + 0], pb[j * 3 + 1], pb[j * 3 + 2], 0.0f);
    for (int j = tid; j < MM; j += FT) batch_out[b * MM + j] = (float)b;
    __syncthreads();

    // ---- all 16 points in registers as 8 packed pairs (r11 layout) ----
    // pair j: indices (2j)*FT+tid (.x) and (2j+1)*FT+tid (.y)
    v2f pxv[8], pyv[8], pzv[8], dv[8];
#pragma unroll
    for (int j = 0; j < 8; ++j) {
        const float4 p0 = pts4[(2 * j) * FT + tid];
        const float4 p1 = pts4[(2 * j + 1) * FT + tid];
        pxv[j] = (v2f){p0.x, p1.x};
        pyv[j] = (v2f){p0.y, p1.y};
        pzv[j] = (v2f){p0.z, p1.z};
        dv[j]  = (v2f){INFINITY, INFINITY};
    }

    int   cur = 0;
    float lx = pb[0], ly = pb[1], lz = pb[2];

    for (int s = 0; s < MM; ++s) {
#pragma clang fp contract(off)
        if (tid == 0) {
            samp[b * MM + s] = cur;
            centers_out[((size_t)b * MM + s) * 3 + 0] = lx;
            centers_out[((size_t)b * MM + s) * 3 + 1] = ly;
            centers_out[((size_t)b * MM + s) * 3 + 2] = lz;
        }
        if (s == MM - 1) break;   // last argmax unused by the reference

        const v2f l2x = (v2f){lx, lx};
        const v2f l2y = (v2f){ly, ly};
        const v2f l2z = (v2f){lz, lz};

        // ---- phase 1 (r11 verbatim): distance update + value-only max ----
        v2f vmax2 = (v2f){-INFINITY, -INFINITY};
#pragma unroll
        for (int j = 0; j < 8; ++j) {
            const v2f dx = pxv[j] - l2x;
            const v2f dy = pyv[j] - l2y;
            const v2f dz = pzv[j] - l2z;
            const v2f d2 = (dx * dx + dy * dy) + dz * dz;   // exact: contract off
            dv[j] = __builtin_elementwise_min(dv[j], d2);   // jnp.minimum, exact
            vmax2 = __builtin_elementwise_max(vmax2, dv[j]);
        }
        const float tv = fmaxf(vmax2.x, vmax2.y);           // thread value max

        // ---- r13 tail: wave max -> SGPR broadcast, exec-sparse index scan ----
        float wv = tv;
        DPP_FMAX6(wv)                              // lane63: wave max
        const float wmax = readlane_f(wv, 63);     // uniform broadcast

        int cand = 0x7fffffff;
        if (tv == wmax) {
            // descending order keeps the LOWEST matching index (ref tie-break);
            // == on stored values is exact (dists >= +0.0, no NaN)
#pragma unroll
            for (int j = 7; j >= 0; --j) {
                cand = (dv[j].y == wmax) ? (2 * j + 1) * FT + tid : cand;
                cand = (dv[j].x == wmax) ? (2 * j) * FT + tid     : cand;
            }
        }
        DPP_IMIN6(cand)                            // lane63: wave min matching idx

        // ---- one slot write, ONE barrier, 8-slot tree, winner fetch ----
        const int par = s & 1;
        if (lane == 63) slots[par][w] = make_float2(wmax, __int_as_float(cand));
        __syncthreads();

        const float2 s0 = slots[par][0], s1 = slots[par][1];
        const float2 s2 = slots[par][2], s3 = slots[par][3];
        const float2 s4 = slots[par][4], s5 = slots[par][5];
        const float2 s6 = slots[par][6], s7 = slots[par][7];
        const float2 a0 = argmax2(s0, s1), a1 = argmax2(s2, s3);
        const float2 a2 = argmax2(s4, s5), a3 = argmax2(s6, s7);
        const float2 b0 = argmax2(a0, a1), b1 = argmax2(a2, a3);
        const float2 win = argmax2(b0, b1);

        cur = __float_as_int(win.y);
        const float4 wp = pts4[cur];               // broadcast read, conflict-free
        lx = wp.x; ly = wp.y; lz = wp.z;
    }
}

// ---------------- Kernel 2: radius-KNN, one wave per center ----------------
#define CAP 256
__global__ __launch_bounds__(256) void knn_kernel(
    const float* __restrict__ pos,
    const int* __restrict__ samp,
    int* __restrict__ nbr,
    int* __restrict__ cntbuf)
{
    const int wave = threadIdx.x >> 6;
    const int lane = threadIdx.x & 63;
    const int c = blockIdx.x * 4 + wave;
    const int b = c >> 11;
    const float* pb = pos + (size_t)b * NN * 3;

    __shared__ float sd2[4][CAP];
    __shared__ int   sid[4][CAP];

    const int ctr = samp[c];
    const float cx = pb[ctr * 3 + 0];
    const float cy = pb[ctr * 3 + 1];
    const float cz = pb[ctr * 3 + 2];
    const float R2 = (float)(0.1 * 0.1);

    int cnt = 0;
    for (int r = 0; r < NN / 64; ++r) {
        const int g = r * 64 + lane;
        float dx = __fsub_rn(cx, pb[g * 3 + 0]);
        float dy = __fsub_rn(cy, pb[g * 3 + 1]);
        float dz = __fsub_rn(cz, pb[g * 3 + 2]);
        float d2 = __fadd_rn(__fadd_rn(__fmul_rn(dx, dx), __fmul_rn(dy, dy)),
                             __fmul_rn(dz, dz));
        const bool pred = (d2 <= R2);
        const unsigned long long mask = __ballot(pred);
        const int before = __popcll(mask & ((1ull << lane) - 1ull));
        if (pred) {
            const int slot = cnt + before;
            if (slot < CAP) { sd2[wave][slot] = d2; sid[wave][slot] = g; }
        }
        cnt += __popcll(mask);
    }
    if (cnt > CAP) cnt = CAP;
    __syncthreads();

    for (int ci = lane; ci < cnt; ci += 64) {
        const float dc = sd2[wave][ci];
        const int   ic = sid[wave][ci];
        int rank = 0;
        for (int j = 0; j < cnt; ++j) {
            const float dj = sd2[wave][j];
            const int   ij = sid[wave][j];
            rank += (dj < dc || (dj == dc && ij < ic)) ? 1 : 0;
        }
        if (rank < KK) nbr[c * KK + rank] = ic;
    }
    if (lane == 0) cntbuf[c] = (cnt < KK) ? cnt : KK;
}

// ---------------- Kernel 3: gather + MLP + max-pool, one wave per center ----
__global__ __launch_bounds__(256) void mlp_kernel(
    const float* __restrict__ x,
    const float* __restrict__ pos,
    const float* __restrict__ W1,
    const float* __restrict__ b1,
    const float* __restrict__ W2,
    const float* __restrict__ b2,
    const int* __restrict__ nbr,
    const int* __restrict__ cntbuf,
    const float* __restrict__ centers,
    float* __restrict__ out)
{
    __shared__ float WT[64 * 68];
    __shared__ float featL[4][32 * 68];

    const int tid = threadIdx.x, wave = tid >> 6, lane = tid & 63;
    const int c = blockIdx.x * 4 + wave;
    const int b = c >> 11;
    const int cnt = cntbuf[c];

    for (int idx = tid; idx < 67 * 64; idx += 256) {
        const int i = idx >> 6, h = idx & 63;
        WT[h * 68 + i] = W1[idx];
    }
    if (tid < 64) WT[tid * 68 + 67] = 0.0f;

    const float ctr0 = centers[c * 3 + 0];
    const float ctr1 = centers[c * 3 + 1];
    const float ctr2 = centers[c * 3 + 2];
    for (int k = 0; k < cnt; ++k) {
        const int j = nbr[c * KK + k];
        featL[wave][k * 68 + lane] = x[((size_t)b * NN + j) * FF + lane];
        if (lane < 3) {
            const float pj = pos[((size_t)b * NN + j) * 3 + lane];
            const float ci = (lane == 0) ? ctr0 : ((lane == 1) ? ctr1 : ctr2);
            featL[wave][k * 68 + 64 + lane] = __fsub_rn(pj, ci);
        }
        if (lane == 3) featL[wave][k * 68 + 67] = 0.0f;
    }
    __syncthreads();

    float wreg[68];
#pragma unroll
    for (int i4 = 0; i4 < 17; ++i4) {
        const float4 v = *(const float4*)&WT[lane * 68 + i4 * 4];
        wreg[i4 * 4 + 0] = v.x; wreg[i4 * 4 + 1] = v.y;
        wreg[i4 * 4 + 2] = v.z; wreg[i4 * 4 + 3] = v.w;
    }
    const float bias1 = b1[lane];
    for (int k = 0; k < cnt; ++k) {
        float acc = bias1;
#pragma unroll
        for (int i4 = 0; i4 < 17; ++i4) {
            const float4 f = *(const float4*)&featL[wave][k * 68 + i4 * 4];
            acc = fmaf(f.x, wreg[i4 * 4 + 0], acc);
            acc = fmaf(f.y, wreg[i4 * 4 + 1], acc);
            acc = fmaf(f.z, wreg[i4 * 4 + 2], acc);
            acc = fmaf(f.w, wreg[i4 * 4 + 3], acc);
        }
        featL[wave][k * 68 + lane] = fmaxf(acc, 0.0f);
    }
    __syncthreads();

    for (int idx = tid; idx < 64 * 64; idx += 256) {
        const int i = idx >> 6, h = idx & 63;
        WT[h * 68 + i] = W2[idx];
    }
    __syncthreads();

#pragma unroll
    for (int i4 = 0; i4 < 16; ++i4) {
        const float4 v = *(const float4*)&WT[lane * 68 + i4 * 4];
        wreg[i4 * 4 + 0] = v.x; wreg[i4 * 4 + 1] = v.y;
        wreg[i4 * 4 + 2] = v.z; wreg[i4 * 4 + 3] = v.w;
    }
    const float bias2 = b2[lane];
    float m = -INFINITY;
    for (int k = 0; k < cnt; ++k) {
        float acc = bias2;
#pragma unroll
        for (int i4 = 0; i4 < 16; ++i4) {
            const float4 f = *(const float4*)&featL[wave][k * 68 + i4 * 4];
            acc = fmaf(f.x, wreg[i4 * 4 + 0], acc);
            acc = fmaf(f.y, wreg[i4 * 4 + 1], acc);
            acc = fmaf(f.z, wreg[i4 * 4 + 2], acc);
            acc = fmaf(f.w, wreg[i4 * 4 + 3], acc);
        }
        m = fmaxf(m, fmaxf(acc, 0.0f));
    }
    out[(size_t)c * HH + lane] = (cnt > 0) ? m : 0.0f;
}

extern "C" void kernel_launch(void* const* d_in, const int* in_sizes, int n_in,
                              void* d_out, int out_size, void* d_ws, size_t ws_size,
                              hipStream_t stream) {
    const float* x   = (const float*)d_in[0];
    const float* pos = (const float*)d_in[1];
    const float* W1  = (const float*)d_in[3];
    const float* b1  = (const float*)d_in[4];
    const float* W2  = (const float*)d_in[5];
    const float* b2  = (const float*)d_in[6];

    float* out         = (float*)d_out;
    float* centers_out = out + (size_t)NB * MM * HH;
    float* batch_out   = centers_out + (size_t)NB * MM * 3;

    char* ws = (char*)d_ws;
    int* samp   = (int*)ws;
    int* cntbuf = (int*)(ws + (size_t)NB * MM * 4);
    int* nbr    = (int*)(ws + (size_t)2 * NB * MM * 4);

    fps_kernel<<<NB, FT, 0, stream>>>(pos, samp, centers_out, batch_out);
    knn_kernel<<<(NB * MM) / 4, 256, 0, stream>>>(pos, samp, nbr, cntbuf);
    mlp_kernel<<<(NB * MM) / 4, 256, 0, stream>>>(x, pos, W1, b1, W2, b2,
                                                  nbr, cntbuf, centers_out, out);
}